// Round 7
// baseline (23.516 us; speedup 1.0000x reference)
//
#include <hip/hip_runtime.h>

// Problem constants (from reference)
#define HH 96
#define WW 96
#define CH 64
#define NHEADS 4
#define DHEAD 16
#define RAD 3
#define BATCH 2
#define PLANE (HH * WW)

// Tiling: 8x8 positions per block, 128 threads = 4 strip-rows x 8 cols x 4 cg.
// Each thread computes TWO vertically adjacent positions (a strip) -> shared
// neighbor rows cut ds_read_b128 count from 98/pos to 56/pos.
#define TS 8
#define HS (TS + 2 * RAD)         // 14 halo side
#define HP (HS * HS)              // 196 halo pixels
#define CPAD 20                   // LDS channel stride (dwords): 16 ch + 4 pad
#define TPD (HH / TS)             // 12
#define TILES (TPD * TPD)         // 144 per (b,head) slab

// DPP quad_perm cross-lane add (VALU pipe, not DS)
template <int CTRL>
__device__ __forceinline__ float qperm(float x) {
    return __int_as_float(
        __builtin_amdgcn_mov_dpp(__float_as_int(x), CTRL, 0xF, 0xF, true));
}

template <bool INTERIOR>
__device__ __forceinline__ void tile_body(
    const float* __restrict__ q, const float* __restrict__ k,
    const float* __restrict__ v, float* __restrict__ out,
    float* __restrict__ lk, float* __restrict__ lv,
    int b, int head, int h0, int w0)
{
    const int tid = threadIdx.x;        // 0..127
    const int cg  = tid & 3;
    const int s   = tid >> 2;           // 0..31 strip id
    const int sx  = s & 7;              // col in tile
    const int sy  = s >> 3;             // strip row 0..3
    const int pyA = 2 * sy;             // position A row (B = A+1)
    const int hA  = h0 + pyA;
    const int w   = w0 + sx;

    // fold softmax scale and log2(e): exp(s/4) = exp2(s * 0.25*log2e)
    const float QS = 0.25f * 1.4426950408889634f;
    const int qoffA = (b * CH + head * DHEAD + cg * 4) * PLANE + hA * WW + w;
    const int qoffB = qoffA + WW;
    const float qa0 = q[qoffA]             * QS;
    const float qa1 = q[qoffA +     PLANE] * QS;
    const float qa2 = q[qoffA + 2 * PLANE] * QS;
    const float qa3 = q[qoffA + 3 * PLANE] * QS;
    const float qb0 = q[qoffB]             * QS;
    const float qb1 = q[qoffB +     PLANE] * QS;
    const float qb2 = q[qoffB + 2 * PLANE] * QS;
    const float qb3 = q[qoffB + 3 * PLANE] * QS;

    // ---- Stage k,v halo (16 ch x 196 px) into LDS ----
    {
        const float* kbase = k + (size_t)(b * CH + head * DHEAD) * PLANE;
        const float* vbase = v + (size_t)(b * CH + head * DHEAD) * PLANE;
        const int hp1 = tid;            // 0..127
        const int hp2 = tid + 128;      // 128..255 (active if < 196)
        int gh1 = h0 - RAD + hp1 / HS, gw1 = w0 - RAD + hp1 % HS;
        int gh2 = h0 - RAD + hp2 / HS, gw2 = w0 - RAD + hp2 % HS;
        if constexpr (!INTERIOR) {
            gh1 = min(max(gh1, 0), HH - 1); gw1 = min(max(gw1, 0), WW - 1);
            gh2 = min(max(gh2, 0), HH - 1); gw2 = min(max(gw2, 0), WW - 1);
        }
        const int ga1 = gh1 * WW + gw1;
        const int ga2 = gh2 * WW + gw2;
        const bool have2 = (hp2 < HP);
#pragma unroll
        for (int ch = 0; ch < 16; ++ch) {
            lk[hp1 * CPAD + ch] = kbase[ch * PLANE + ga1];
            lv[hp1 * CPAD + ch] = vbase[ch * PLANE + ga1];
            if (have2) {
                lk[hp2 * CPAD + ch] = kbase[ch * PLANE + ga2];
                lv[hp2 * CPAD + ch] = vbase[ch * PLANE + ga2];
            }
        }
    }
    __syncthreads();

    // ---- Column validity (edges only); row validity per rr below ----
    bool colok[7];
    if constexpr (!INTERIOR) {
#pragma unroll
        for (int dd = 0; dd < 7; ++dd)
            colok[dd] = ((unsigned)(w + dd - RAD) < (unsigned)WW);
    }

    float ssA = 0.f, ssB = 0.f;
    float oA0 = 0.f, oA1 = 0.f, oA2 = 0.f, oA3 = 0.f;
    float oB0 = 0.f, oB1 = 0.f, oB2 = 0.f, oB3 = 0.f;

    // base dword index of halo pixel (row pyA, col sx) = A's (dy=-3,dx=-3)
    const int lbase = (pyA * HS + sx) * CPAD + cg * 4;

#pragma unroll
    for (int rr = 0; rr < 8; ++rr) {
        // halo row pyA+rr = global row hA+rr-3 for BOTH positions
        bool rowok = true;
        if constexpr (!INTERIOR)
            rowok = ((unsigned)(hA + rr - RAD) < (unsigned)HH);
#pragma unroll
        for (int dd = 0; dd < 7; ++dd) {
            const int li = lbase + (rr * HS + dd) * CPAD;
            const float4 kv = *reinterpret_cast<const float4*>(&lk[li]);
            const float4 vv = *reinterpret_cast<const float4*>(&lv[li]);

            float sA, sB;
            if (rr <= 6) {
                sA = qa0 * kv.x;
                sA = fmaf(qa1, kv.y, sA);
                sA = fmaf(qa2, kv.z, sA);
                sA = fmaf(qa3, kv.w, sA);
                sA += qperm<0xB1>(sA);     // xor 1
                sA += qperm<0x4E>(sA);     // xor 2
            }
            if (rr >= 1) {
                sB = qb0 * kv.x;
                sB = fmaf(qb1, kv.y, sB);
                sB = fmaf(qb2, kv.z, sB);
                sB = fmaf(qb3, kv.w, sB);
                sB += qperm<0xB1>(sB);
                sB += qperm<0x4E>(sB);
            }
            bool ok = true;
            if constexpr (!INTERIOR) ok = rowok && colok[dd];

            if (rr <= 6) {                  // position A: dyA = rr-3
                const float x = ok ? sA : -1000.f;
                const float p = __builtin_amdgcn_exp2f(x);
                ssA += p;
                oA0 = fmaf(p, vv.x, oA0);
                oA1 = fmaf(p, vv.y, oA1);
                oA2 = fmaf(p, vv.z, oA2);
                oA3 = fmaf(p, vv.w, oA3);
            }
            if (rr >= 1) {                  // position B: dyB = rr-4
                const float x = ok ? sB : -1000.f;
                const float p = __builtin_amdgcn_exp2f(x);
                ssB += p;
                oB0 = fmaf(p, vv.x, oB0);
                oB1 = fmaf(p, vv.y, oB1);
                oB2 = fmaf(p, vv.z, oB2);
                oB3 = fmaf(p, vv.w, oB3);
            }
        }
    }

    const float invA = 1.0f / ssA;
    const float invB = 1.0f / ssB;
    out[qoffA]             = oA0 * invA;
    out[qoffA +     PLANE] = oA1 * invA;
    out[qoffA + 2 * PLANE] = oA2 * invA;
    out[qoffA + 3 * PLANE] = oA3 * invA;
    out[qoffB]             = oB0 * invB;
    out[qoffB +     PLANE] = oB1 * invB;
    out[qoffB + 2 * PLANE] = oB2 * invB;
    out[qoffB + 3 * PLANE] = oB3 * invB;
}

__global__ __launch_bounds__(128) void natten_strip(
    const float* __restrict__ q, const float* __restrict__ k,
    const float* __restrict__ v, float* __restrict__ out)
{
    __shared__ __align__(16) float lk[HP * CPAD];   // 15,680 B
    __shared__ __align__(16) float lv[HP * CPAD];   // total 31,360 B

    const int bid  = (int)blockIdx.x;
    const int slab = bid & 7;            // one (b,head) per XCD
    const int tile = bid >> 3;           // 0..143
    const int b = slab >> 2, head = slab & 3;
    const int ty = tile / TPD, tx = tile % TPD;
    const int h0 = ty * TS, w0 = tx * TS;

    const bool interior = (ty >= 1) && (ty <= TPD - 2) &&
                          (tx >= 1) && (tx <= TPD - 2);
    if (interior)
        tile_body<true >(q, k, v, out, lk, lv, b, head, h0, w0);
    else
        tile_body<false>(q, k, v, out, lk, lv, b, head, h0, w0);
}

extern "C" void kernel_launch(void* const* d_in, const int* in_sizes, int n_in,
                              void* d_out, int out_size, void* d_ws, size_t ws_size,
                              hipStream_t stream) {
    const float* q = (const float*)d_in[0];
    const float* k = (const float*)d_in[1];
    const float* v = (const float*)d_in[2];
    float* out = (float*)d_out;

    const int grid = BATCH * NHEADS * TILES;   // 1152
    natten_strip<<<grid, 128, 0, stream>>>(q, k, v, out);
}

// Round 8
// 19.273 us; speedup vs baseline: 1.2201x; 1.2201x over previous
//
#include <hip/hip_runtime.h>

// Problem constants (from reference)
#define HH 96
#define WW 96
#define CH 64
#define NHEADS 4
#define DHEAD 16
#define RAD 3
#define BATCH 2
#define PLANE (HH * WW)

// Tiling: 8x8 positions/block, 256 threads = 64 pos x 4 channel-groups.
// k,v staged in LDS as fp16: per pixel 20 dwords = 8 k-half2 | 8 v-half2 |
// 4 pad (80B stride -> same <=2-way bank pattern as fp32 CPAD=20, but half
// the LDS: 15,680B -> 8 blocks/CU = 32 waves/CU, 2x R6's occupancy).
#define TS 8
#define HS (TS + 2 * RAD)         // 14 halo side
#define HP (HS * HS)              // 196 halo pixels
#define PSTRIDE 20                // dwords per pixel in LDS
#define TPD (HH / TS)             // 12
#define TILES (TPD * TPD)         // 144 per (b,head) slab

typedef _Float16 h2 __attribute__((ext_vector_type(2)));
union H2U { unsigned int u; h2 h; };

// DPP quad_perm cross-lane add (VALU pipe, not DS)
template <int CTRL>
__device__ __forceinline__ float qperm(float x) {
    return __int_as_float(
        __builtin_amdgcn_mov_dpp(__float_as_int(x), CTRL, 0xF, 0xF, true));
}

__device__ __forceinline__ float dot4(h2 k01, h2 k23, h2 q01, h2 q23) {
#if __has_builtin(__builtin_amdgcn_fdot2)
    return __builtin_amdgcn_fdot2(k01, q01,
           __builtin_amdgcn_fdot2(k23, q23, 0.0f, false), false);
#else
    float s =      (float)k01.x * (float)q01.x;
    s = fmaf((float)k01.y, (float)q01.y, s);
    s = fmaf((float)k23.x, (float)q23.x, s);
    s = fmaf((float)k23.y, (float)q23.y, s);
    return s;
#endif
}

template <bool INTERIOR>
__device__ __forceinline__ void tile_body(
    const float* __restrict__ q, const float* __restrict__ k,
    const float* __restrict__ v, float* __restrict__ out,
    unsigned int* __restrict__ lkv,
    int b, int head, int h0, int w0)
{
    const int tid = threadIdx.x;
    const int cg  = tid & 3;
    const int pos = tid >> 2;          // 0..63
    const int px  = pos & 7, py = pos >> 3;
    const int h = h0 + py, w = w0 + px;

    // q for this thread's 4 channels, pre-scaled by 0.25*log2(e), cvt fp16
    const float QS = 0.25f * 1.4426950408889634f;
    const int qoff = (b * CH + head * DHEAD + cg * 4) * PLANE + h * WW + w;
    h2 q01, q23;
    q01.x = (_Float16)(q[qoff]             * QS);
    q01.y = (_Float16)(q[qoff +     PLANE] * QS);
    q23.x = (_Float16)(q[qoff + 2 * PLANE] * QS);
    q23.y = (_Float16)(q[qoff + 3 * PLANE] * QS);

    // ---- Stage k,v halo (196 px x 16 ch, fp16) ----
    {
        const float* kbase = k + (size_t)(b * CH + head * DHEAD) * PLANE;
        const float* vbase = v + (size_t)(b * CH + head * DHEAD) * PLANE;
#pragma unroll
        for (int it = 0; it < 7; ++it) {
            const int d = it * 256 + tid;          // (pix, chan-pair)
            if (d < HP * 8) {                      // 1568
                const int chp = d & 7;             // half2 pair 0..7
                const int pix = d >> 3;            // 0..195
                int gh = h0 - RAD + pix / HS;
                int gw = w0 - RAD + pix % HS;
                if constexpr (!INTERIOR) {
                    gh = min(max(gh, 0), HH - 1);
                    gw = min(max(gw, 0), WW - 1);
                }
                const int ga = gh * WW + gw;
                const int c2 = chp * 2;
                H2U kp, vp;
                kp.h.x = (_Float16)kbase[c2 * PLANE + ga];
                kp.h.y = (_Float16)kbase[(c2 + 1) * PLANE + ga];
                vp.h.x = (_Float16)vbase[c2 * PLANE + ga];
                vp.h.y = (_Float16)vbase[(c2 + 1) * PLANE + ga];
                lkv[pix * PSTRIDE + chp]     = kp.u;
                lkv[pix * PSTRIDE + 8 + chp] = vp.u;
            }
        }
    }
    __syncthreads();

    // ---- Column validity (edge tiles only) ----
    bool colok[7];
    if constexpr (!INTERIOR) {
#pragma unroll
        for (int dd = 0; dd < 7; ++dd)
            colok[dd] = ((unsigned)(w + dd - RAD) < (unsigned)WW);
    }

    float ssum = 0.f;
    float o0 = 0.f, o1 = 0.f, o2 = 0.f, o3 = 0.f;

    // dword index of this thread's (dy=-3,dx=-3) neighbor pixel, cg chunk
    const int lbase = (py * HS + px) * PSTRIDE + cg * 2;

#pragma unroll
    for (int dy = -RAD; dy <= RAD; ++dy) {
        bool rowok = true;
        if constexpr (!INTERIOR)
            rowok = ((unsigned)(h + dy) < (unsigned)HH);
#pragma unroll
        for (int dx = -RAD; dx <= RAD; ++dx) {
            const int li = lbase + ((dy + RAD) * HS + (dx + RAD)) * PSTRIDE;
            const uint2 kk = *reinterpret_cast<const uint2*>(&lkv[li]);
            const uint2 vv = *reinterpret_cast<const uint2*>(&lkv[li + 8]);

            H2U k01, k23; k01.u = kk.x; k23.u = kk.y;
            float s = dot4(k01.h, k23.h, q01, q23);
            s += qperm<0xB1>(s);   // xor 1
            s += qperm<0x4E>(s);   // xor 2

            bool ok = true;
            if constexpr (!INTERIOR) ok = rowok && colok[dx + RAD];
            const float x = ok ? s : -1000.f;
            const float p = __builtin_amdgcn_exp2f(x);
            ssum += p;

            H2U v01, v23; v01.u = vv.x; v23.u = vv.y;
            o0 = fmaf(p, (float)v01.h.x, o0);
            o1 = fmaf(p, (float)v01.h.y, o1);
            o2 = fmaf(p, (float)v23.h.x, o2);
            o3 = fmaf(p, (float)v23.h.y, o3);
        }
    }

    const float inv = 1.0f / ssum;
    out[qoff]             = o0 * inv;
    out[qoff +     PLANE] = o1 * inv;
    out[qoff + 2 * PLANE] = o2 * inv;
    out[qoff + 3 * PLANE] = o3 * inv;
}

__global__ __launch_bounds__(256, 8) void natten_h16(
    const float* __restrict__ q, const float* __restrict__ k,
    const float* __restrict__ v, float* __restrict__ out)
{
    __shared__ __align__(16) unsigned int lkv[HP * PSTRIDE];  // 15,680 B

    const int bid  = (int)blockIdx.x;
    const int slab = bid & 7;            // one (b,head) per XCD
    const int tile = bid >> 3;           // 0..143
    const int b = slab >> 2, head = slab & 3;
    const int ty = tile / TPD, tx = tile % TPD;
    const int h0 = ty * TS, w0 = tx * TS;

    const bool interior = (ty >= 1) && (ty <= TPD - 2) &&
                          (tx >= 1) && (tx <= TPD - 2);
    if (interior)
        tile_body<true >(q, k, v, out, lkv, b, head, h0, w0);
    else
        tile_body<false>(q, k, v, out, lkv, b, head, h0, w0);
}

extern "C" void kernel_launch(void* const* d_in, const int* in_sizes, int n_in,
                              void* d_out, int out_size, void* d_ws, size_t ws_size,
                              hipStream_t stream) {
    const float* q = (const float*)d_in[0];
    const float* k = (const float*)d_in[1];
    const float* v = (const float*)d_in[2];
    float* out = (float*)d_out;

    const int grid = BATCH * NHEADS * TILES;   // 1152
    natten_h16<<<grid, 256, 0, stream>>>(q, k, v, out);
}